// Round 1
// baseline (2517.875 us; speedup 1.0000x reference)
//
#include <hip/hip_runtime.h>

#define BB 16384
#define NN 20
#define DD 64
#define IMGK 2048

__device__ __forceinline__ float waveReduceSum(float x) {
#pragma unroll
  for (int off = 32; off > 0; off >>= 1) x += __shfl_xor(x, off, 64);
  return x;
}

// ---------------- Kernel A: img = image @ W_image_w + W_image_b + b_image ----------------
// [16384 x 2048] @ [2048 x 64] -> [16384 x 64], f32, tiled 32x64, K-tile 64.
__global__ __launch_bounds__(256, 2)
void img_gemm_kernel(const float* __restrict__ img_in,
                     const float* __restrict__ Ww,
                     const float* __restrict__ Wb,
                     const float* __restrict__ bimg,
                     float* __restrict__ img_out) {
  __shared__ float Alds[64][36];   // transposed: Alds[k][r]
  __shared__ float Blds[64][68];   // Blds[k][n]
  const int t = threadIdx.x;
  const int row0 = blockIdx.x * 32;
  const int tx = t & 15, ty = t >> 4;
  const int ar = t >> 3, akq = (t & 7) * 8;
  const int bk = t >> 2, bnq = (t & 3) * 16;
  float acc[2][4] = {{0.f, 0.f, 0.f, 0.f}, {0.f, 0.f, 0.f, 0.f}};
  for (int k0 = 0; k0 < IMGK; k0 += 64) {
#pragma unroll
    for (int j = 0; j < 2; ++j) {
      float4 va = *reinterpret_cast<const float4*>(
          &img_in[(size_t)(row0 + ar) * IMGK + k0 + akq + 4 * j]);
      int kk = akq + 4 * j;
      Alds[kk + 0][ar] = va.x;
      Alds[kk + 1][ar] = va.y;
      Alds[kk + 2][ar] = va.z;
      Alds[kk + 3][ar] = va.w;
    }
#pragma unroll
    for (int j = 0; j < 4; ++j) {
      float4 vb = *reinterpret_cast<const float4*>(
          &Ww[(size_t)(k0 + bk) * 64 + bnq + 4 * j]);
      *reinterpret_cast<float4*>(&Blds[bk][bnq + 4 * j]) = vb;
    }
    __syncthreads();
#pragma unroll 8
    for (int k = 0; k < 64; ++k) {
      float2 a = *reinterpret_cast<const float2*>(&Alds[k][ty * 2]);
      float4 b = *reinterpret_cast<const float4*>(&Blds[k][tx * 4]);
      acc[0][0] = fmaf(a.x, b.x, acc[0][0]);
      acc[0][1] = fmaf(a.x, b.y, acc[0][1]);
      acc[0][2] = fmaf(a.x, b.z, acc[0][2]);
      acc[0][3] = fmaf(a.x, b.w, acc[0][3]);
      acc[1][0] = fmaf(a.y, b.x, acc[1][0]);
      acc[1][1] = fmaf(a.y, b.y, acc[1][1]);
      acc[1][2] = fmaf(a.y, b.z, acc[1][2]);
      acc[1][3] = fmaf(a.y, b.w, acc[1][3]);
    }
    __syncthreads();
  }
  float4 wb = *reinterpret_cast<const float4*>(&Wb[tx * 4]);
  float4 bi = *reinterpret_cast<const float4*>(&bimg[tx * 4]);
#pragma unroll
  for (int i = 0; i < 2; ++i) {
    float4 o;
    o.x = acc[i][0] + wb.x + bi.x;
    o.y = acc[i][1] + wb.y + bi.y;
    o.z = acc[i][2] + wb.z + bi.z;
    o.w = acc[i][3] + wb.w + bi.w;
    *reinterpret_cast<float4*>(&img_out[(size_t)(row0 + ty * 2 + i) * 64 + tx * 4]) = o;
  }
}

// ---------------- Kernel B1: ingredient-level attention -> ingre_att [B x 64] ----------------
__global__ __launch_bounds__(256, 2)
void ingre_att_kernel(const int* __restrict__ user_input,
                      const int* __restrict__ ingre_input,
                      const int* __restrict__ ingre_num,
                      const float* __restrict__ user_emb,
                      const float* __restrict__ ingre_emb,
                      const float* __restrict__ Wi,    // [192][64]
                      const float* __restrict__ Wib,   // [64]
                      const float* __restrict__ bat,   // [64]
                      const float* __restrict__ v,     // [64]
                      const float* __restrict__ ws_img,
                      float* __restrict__ ws_ia) {
  __shared__ float Wilds[192 * 64];
  __shared__ float qe_s[4][20][64];
  __shared__ float x_s[4][128];
  __shared__ float bias_s[64];
  __shared__ float v_s[64];
  const int t = threadIdx.x;
  for (int i = t; i < 192 * 64 / 4; i += 256)
    reinterpret_cast<float4*>(Wilds)[i] = reinterpret_cast<const float4*>(Wi)[i];
  if (t < 64) {
    bias_s[t] = Wib[t] + bat[t];
    v_s[t] = v[t];
  }
  __syncthreads();
  const int wave = t >> 6, lane = t & 63;
  for (int bi = 0; bi < 4; ++bi) {
    const int b = blockIdx.x * 16 + wave * 4 + bi;
    const int u = user_input[b];
    x_s[wave][lane] = user_emb[(size_t)u * 64 + lane];
    x_s[wave][64 + lane] = ws_img[(size_t)b * 64 + lane];
#pragma unroll
    for (int n = 0; n < NN; ++n) {
      const int gi = ingre_input[b * NN + n];
      qe_s[wave][n][lane] = ingre_emb[(size_t)gi * 64 + lane];
    }
    __syncthreads();
    // base[w] from [ue | img] against W rows 64..191
    float base = bias_s[lane];
    const float4* x4 = reinterpret_cast<const float4*>(&x_s[wave][0]);
#pragma unroll
    for (int d0 = 0; d0 < 32; ++d0) {
      float4 q = x4[d0];
      int d = 64 + d0 * 4;
      base = fmaf(q.x, Wilds[(d + 0) * 64 + lane],
             fmaf(q.y, Wilds[(d + 1) * 64 + lane],
             fmaf(q.z, Wilds[(d + 2) * 64 + lane],
             fmaf(q.w, Wilds[(d + 3) * 64 + lane], base))));
    }
    float accn[NN];
#pragma unroll
    for (int n = 0; n < NN; ++n) accn[n] = 0.f;
#pragma unroll
    for (int d0 = 0; d0 < 16; ++d0) {
      const int d = d0 * 4;
      const float w0 = Wilds[(d + 0) * 64 + lane];
      const float w1 = Wilds[(d + 1) * 64 + lane];
      const float w2 = Wilds[(d + 2) * 64 + lane];
      const float w3 = Wilds[(d + 3) * 64 + lane];
#pragma unroll
      for (int n = 0; n < NN; ++n) {
        float4 q = reinterpret_cast<const float4*>(&qe_s[wave][n][0])[d0];
        accn[n] = fmaf(q.x, w0, fmaf(q.y, w1, fmaf(q.z, w2, fmaf(q.w, w3, accn[n]))));
      }
    }
    const int num = ingre_num[b];
#pragma unroll
    for (int n = 0; n < NN; ++n) {
      float tv = tanhf(accn[n] + base) * v_s[lane];
      tv = waveReduceSum(tv);
      accn[n] = (n < num) ? tv : -1e12f;
    }
    float m = accn[0];
#pragma unroll
    for (int n = 1; n < NN; ++n) m = fmaxf(m, accn[n]);
    float ssum = 0.f;
#pragma unroll
    for (int n = 0; n < NN; ++n) {
      accn[n] = expf(accn[n] - m);
      ssum += accn[n];
    }
    const float inv = 1.0f / ssum;
    float ia = 0.f;
#pragma unroll
    for (int n = 0; n < NN; ++n) ia = fmaf(accn[n], qe_s[wave][n][lane], ia);
    ws_ia[(size_t)b * 64 + lane] = ia * inv;
    __syncthreads();
  }
}

// ---------------- Kernel B2: component scores -> flat [3B] (block-concat order) ----------------
__global__ __launch_bounds__(256, 2)
void com_score_kernel(const int* __restrict__ user_input,
                      const int* __restrict__ item_input,
                      const float* __restrict__ user_emb,
                      const float* __restrict__ item_emb,
                      const float* __restrict__ Wc,    // [128][64]
                      const float* __restrict__ Wcb,   // [64]
                      const float* __restrict__ bat,   // [64]
                      const float* __restrict__ vc,    // [64]
                      const float* __restrict__ ws_img,
                      const float* __restrict__ ws_ia,
                      float* __restrict__ ws_flat) {
  __shared__ float Wclds[128 * 64];
  __shared__ float x_s[4][4][64];
  __shared__ float bias_s[64];
  __shared__ float vc_s[64];
  const int t = threadIdx.x;
  for (int i = t; i < 128 * 64 / 4; i += 256)
    reinterpret_cast<float4*>(Wclds)[i] = reinterpret_cast<const float4*>(Wc)[i];
  if (t < 64) {
    bias_s[t] = Wcb[t] + bat[t];
    vc_s[t] = vc[t];
  }
  __syncthreads();
  const int wave = t >> 6, lane = t & 63;
  for (int bi = 0; bi < 4; ++bi) {
    const int b = blockIdx.x * 16 + wave * 4 + bi;
    const int u = user_input[b];
    const int it = item_input[b];
    x_s[wave][0][lane] = user_emb[(size_t)u * 64 + lane];
    x_s[wave][1][lane] = item_emb[(size_t)it * 64 + lane];
    x_s[wave][2][lane] = ws_ia[(size_t)b * 64 + lane];
    x_s[wave][3][lane] = ws_img[(size_t)b * 64 + lane];
    __syncthreads();
    const float4* u4 = reinterpret_cast<const float4*>(&x_s[wave][0][0]);
    float up = 0.f;
#pragma unroll
    for (int d0 = 0; d0 < 16; ++d0) {
      float4 q = u4[d0];
      int d = d0 * 4;
      up = fmaf(q.x, Wclds[(d + 0) * 64 + lane],
           fmaf(q.y, Wclds[(d + 1) * 64 + lane],
           fmaf(q.z, Wclds[(d + 2) * 64 + lane],
           fmaf(q.w, Wclds[(d + 3) * 64 + lane], up))));
    }
    float sc[3];
#pragma unroll
    for (int c = 0; c < 3; ++c) {
      const float4* y4 = reinterpret_cast<const float4*>(&x_s[wave][1 + c][0]);
      float s = bias_s[lane] + up;
#pragma unroll
      for (int d0 = 0; d0 < 16; ++d0) {
        float4 q = y4[d0];
        int d = 64 + d0 * 4;
        s = fmaf(q.x, Wclds[(d + 0) * 64 + lane],
            fmaf(q.y, Wclds[(d + 1) * 64 + lane],
            fmaf(q.z, Wclds[(d + 2) * 64 + lane],
            fmaf(q.w, Wclds[(d + 3) * 64 + lane], s))));
      }
      sc[c] = waveReduceSum(tanhf(s) * vc_s[lane]);
    }
    if (lane == 0) {
      ws_flat[b] = sc[0];
      ws_flat[BB + b] = sc[1];
      ws_flat[2 * BB + b] = sc[2];
    }
    __syncthreads();
  }
}

// ---------------- Kernel C: head. scores[i][j] = flat[3i+j] (faithful reshape quirk) ----------------
__global__ __launch_bounds__(256, 2)
void head_kernel(const int* __restrict__ user_input,
                 const int* __restrict__ item_input,
                 const float* __restrict__ user_emb,
                 const float* __restrict__ item_emb,
                 const float* __restrict__ Wcat,   // [192][64]
                 const float* __restrict__ Wcatb,  // [64]
                 const float* __restrict__ bcat,   // [64]
                 const float* __restrict__ hw,     // [64]
                 const float* __restrict__ hb,     // [1]
                 const float* __restrict__ ws_img,
                 const float* __restrict__ ws_ia,
                 const float* __restrict__ ws_flat,
                 float* __restrict__ out) {
  __shared__ float Wlds[192 * 64];
  __shared__ float ue_s[4][64];
  __shared__ float itt_s[4][64];
  __shared__ float bias_s[64];
  __shared__ float hw_s[64];
  const int t = threadIdx.x;
  for (int i = t; i < 192 * 64 / 4; i += 256)
    reinterpret_cast<float4*>(Wlds)[i] = reinterpret_cast<const float4*>(Wcat)[i];
  if (t < 64) {
    bias_s[t] = Wcatb[t] + bcat[t];
    hw_s[t] = hw[t];
  }
  __syncthreads();
  const float hbv = hb[0];
  const int wave = t >> 6, lane = t & 63;
  for (int bi = 0; bi < 4; ++bi) {
    const int b = blockIdx.x * 16 + wave * 4 + bi;
    const float s0 = ws_flat[3 * b + 0];
    const float s1 = ws_flat[3 * b + 1];
    const float s2 = ws_flat[3 * b + 2];
    const float m = fmaxf(s0, fmaxf(s1, s2));
    const float e0 = expf(s0 - m), e1 = expf(s1 - m), e2 = expf(s2 - m);
    const float inv = 1.0f / (e0 + e1 + e2);
    const int u = user_input[b];
    const int it = item_input[b];
    const float uev = user_emb[(size_t)u * 64 + lane];
    const float itt = (e0 * item_emb[(size_t)it * 64 + lane] +
                       e1 * ws_ia[(size_t)b * 64 + lane] +
                       e2 * ws_img[(size_t)b * 64 + lane]) * inv;
    ue_s[wave][lane] = uev;
    itt_s[wave][lane] = itt;
    __syncthreads();
    const float4* u4 = reinterpret_cast<const float4*>(&ue_s[wave][0]);
    const float4* i4 = reinterpret_cast<const float4*>(&itt_s[wave][0]);
    float h = bias_s[lane];
#pragma unroll
    for (int d0 = 0; d0 < 16; ++d0) {
      float4 uu = u4[d0];
      float4 ii = i4[d0];
      int d = d0 * 4;
      h = fmaf(uu.x, Wlds[(d + 0) * 64 + lane], h);
      h = fmaf(ii.x, Wlds[(64 + d + 0) * 64 + lane], h);
      h = fmaf(uu.x * ii.x, Wlds[(128 + d + 0) * 64 + lane], h);
      h = fmaf(uu.y, Wlds[(d + 1) * 64 + lane], h);
      h = fmaf(ii.y, Wlds[(64 + d + 1) * 64 + lane], h);
      h = fmaf(uu.y * ii.y, Wlds[(128 + d + 1) * 64 + lane], h);
      h = fmaf(uu.z, Wlds[(d + 2) * 64 + lane], h);
      h = fmaf(ii.z, Wlds[(64 + d + 2) * 64 + lane], h);
      h = fmaf(uu.z * ii.z, Wlds[(128 + d + 2) * 64 + lane], h);
      h = fmaf(uu.w, Wlds[(d + 3) * 64 + lane], h);
      h = fmaf(ii.w, Wlds[(64 + d + 3) * 64 + lane], h);
      h = fmaf(uu.w * ii.w, Wlds[(128 + d + 3) * 64 + lane], h);
    }
    h = fmaxf(h, 0.f) * hw_s[lane];
    float o = waveReduceSum(h);
    if (lane == 0) out[b] = o + hbv;
    __syncthreads();
  }
}

extern "C" void kernel_launch(void* const* d_in, const int* in_sizes, int n_in,
                              void* d_out, int out_size, void* d_ws, size_t ws_size,
                              hipStream_t stream) {
  (void)in_sizes; (void)n_in; (void)out_size; (void)ws_size;
  const int* user_input = (const int*)d_in[0];
  const int* item_input = (const int*)d_in[1];
  const int* ingre_input = (const int*)d_in[2];
  const float* image_input = (const float*)d_in[3];
  const int* ingre_num = (const int*)d_in[4];
  const float* user_emb = (const float*)d_in[5];
  const float* item_emb = (const float*)d_in[6];
  const float* ingre_emb = (const float*)d_in[7];
  const float* W_image_w = (const float*)d_in[8];
  const float* W_image_b = (const float*)d_in[9];
  const float* b_image = (const float*)d_in[10];
  const float* W_concat_w = (const float*)d_in[11];
  const float* W_concat_b = (const float*)d_in[12];
  const float* b_concat = (const float*)d_in[13];
  const float* h_w = (const float*)d_in[14];
  const float* h_b = (const float*)d_in[15];
  const float* W_att_ingre_w = (const float*)d_in[16];
  const float* W_att_ingre_b = (const float*)d_in[17];
  const float* b_att_ingre = (const float*)d_in[18];
  const float* v = (const float*)d_in[19];
  const float* W_att_com_w = (const float*)d_in[20];
  const float* W_att_com_b = (const float*)d_in[21];
  const float* b_att_com = (const float*)d_in[22];
  const float* v_c = (const float*)d_in[23];

  float* ws = (float*)d_ws;
  float* ws_img = ws;                              // [B*64]
  float* ws_ia = ws + (size_t)BB * 64;             // [B*64]
  float* ws_flat = ws + (size_t)2 * BB * 64;       // [3B]
  float* out = (float*)d_out;

  img_gemm_kernel<<<BB / 32, 256, 0, stream>>>(image_input, W_image_w, W_image_b,
                                               b_image, ws_img);
  ingre_att_kernel<<<BB / 16, 256, 0, stream>>>(user_input, ingre_input, ingre_num,
                                                user_emb, ingre_emb,
                                                W_att_ingre_w, W_att_ingre_b, b_att_ingre,
                                                v, ws_img, ws_ia);
  com_score_kernel<<<BB / 16, 256, 0, stream>>>(user_input, item_input, user_emb, item_emb,
                                                W_att_com_w, W_att_com_b, b_att_com, v_c,
                                                ws_img, ws_ia, ws_flat);
  head_kernel<<<BB / 16, 256, 0, stream>>>(user_input, item_input, user_emb, item_emb,
                                           W_concat_w, W_concat_b, b_concat, h_w, h_b,
                                           ws_img, ws_ia, ws_flat, out);
}

// Round 2
// 263.141 us; speedup vs baseline: 9.5686x; 9.5686x over previous
//
#include <hip/hip_runtime.h>

#define BB 16384
#define NN 20
#define DD 64
#define IMGK 2048

__device__ __forceinline__ float waveReduceSum(float x) {
#pragma unroll
  for (int off = 32; off > 0; off >>= 1) x += __shfl_xor(x, off, 64);
  return x;
}

__device__ __forceinline__ float fast_tanh(float x) {
  x = fminf(fmaxf(x, -15.f), 15.f);
  float e = __expf(2.f * x);
  return __fdividef(e - 1.f, e + 1.f);
}

// ---------------- Kernel A: img = image @ W_image_w + W_image_b + b_image ----------------
__global__ __launch_bounds__(256, 2)
void img_gemm_kernel(const float* __restrict__ img_in,
                     const float* __restrict__ Ww,
                     const float* __restrict__ Wb,
                     const float* __restrict__ bimg,
                     float* __restrict__ img_out) {
  __shared__ float Alds[64][36];   // transposed: Alds[k][r]
  __shared__ float Blds[64][68];   // Blds[k][n]
  const int t = threadIdx.x;
  const int row0 = blockIdx.x * 32;
  const int tx = t & 15, ty = t >> 4;
  const int ar = t >> 3, akq = (t & 7) * 8;
  const int bk = t >> 2, bnq = (t & 3) * 16;
  float acc[2][4] = {{0.f, 0.f, 0.f, 0.f}, {0.f, 0.f, 0.f, 0.f}};
  for (int k0 = 0; k0 < IMGK; k0 += 64) {
#pragma unroll
    for (int j = 0; j < 2; ++j) {
      float4 va = *reinterpret_cast<const float4*>(
          &img_in[(size_t)(row0 + ar) * IMGK + k0 + akq + 4 * j]);
      int kk = akq + 4 * j;
      Alds[kk + 0][ar] = va.x;
      Alds[kk + 1][ar] = va.y;
      Alds[kk + 2][ar] = va.z;
      Alds[kk + 3][ar] = va.w;
    }
#pragma unroll
    for (int j = 0; j < 4; ++j) {
      float4 vb = *reinterpret_cast<const float4*>(
          &Ww[(size_t)(k0 + bk) * 64 + bnq + 4 * j]);
      *reinterpret_cast<float4*>(&Blds[bk][bnq + 4 * j]) = vb;
    }
    __syncthreads();
#pragma unroll 8
    for (int k = 0; k < 64; ++k) {
      float2 a = *reinterpret_cast<const float2*>(&Alds[k][ty * 2]);
      float4 b = *reinterpret_cast<const float4*>(&Blds[k][tx * 4]);
      acc[0][0] = fmaf(a.x, b.x, acc[0][0]);
      acc[0][1] = fmaf(a.x, b.y, acc[0][1]);
      acc[0][2] = fmaf(a.x, b.z, acc[0][2]);
      acc[0][3] = fmaf(a.x, b.w, acc[0][3]);
      acc[1][0] = fmaf(a.y, b.x, acc[1][0]);
      acc[1][1] = fmaf(a.y, b.y, acc[1][1]);
      acc[1][2] = fmaf(a.y, b.z, acc[1][2]);
      acc[1][3] = fmaf(a.y, b.w, acc[1][3]);
    }
    __syncthreads();
  }
  float4 wb = *reinterpret_cast<const float4*>(&Wb[tx * 4]);
  float4 bi = *reinterpret_cast<const float4*>(&bimg[tx * 4]);
#pragma unroll
  for (int i = 0; i < 2; ++i) {
    float4 o;
    o.x = acc[i][0] + wb.x + bi.x;
    o.y = acc[i][1] + wb.y + bi.y;
    o.z = acc[i][2] + wb.z + bi.z;
    o.w = acc[i][3] + wb.w + bi.w;
    *reinterpret_cast<float4*>(&img_out[(size_t)(row0 + ty * 2 + i) * 64 + tx * 4]) = o;
  }
}

// ---------------- Kernel A2: base[b][w] = [ue|img] @ Wi[64:192] + Wib + bai ----------------
__global__ __launch_bounds__(256, 4)
void base_kernel(const int* __restrict__ user_input,
                 const float* __restrict__ user_emb,
                 const float* __restrict__ ws_img,
                 const float* __restrict__ Wi,    // [192][64]
                 const float* __restrict__ Wib,   // [64]
                 const float* __restrict__ bai,   // [64]
                 float* __restrict__ ws_base) {
  __shared__ float W_s[128 * 64];
  __shared__ float x_s[4][128];
  const int t = threadIdx.x;
  for (int i = t; i < 128 * 64 / 4; i += 256)
    reinterpret_cast<float4*>(W_s)[i] =
        reinterpret_cast<const float4*>(Wi + 64 * 64)[i];
  __syncthreads();
  const int wave = t >> 6, lane = t & 63;
  const float bb = Wib[lane] + bai[lane];
  const int b0 = blockIdx.x * 32 + wave * 8;
#pragma unroll 1
  for (int bi = 0; bi < 8; ++bi) {
    const int b = b0 + bi;
    const int u = user_input[b];
    x_s[wave][lane] = user_emb[(size_t)u * 64 + lane];
    x_s[wave][64 + lane] = ws_img[(size_t)b * 64 + lane];
    asm volatile("s_waitcnt lgkmcnt(0)" ::: "memory");
    float acc = bb;
    const float4* x4 = reinterpret_cast<const float4*>(&x_s[wave][0]);
#pragma unroll
    for (int d0 = 0; d0 < 32; ++d0) {
      float4 q = x4[d0];
      int d = d0 * 4;
      acc = fmaf(q.x, W_s[(d + 0) * 64 + lane],
            fmaf(q.y, W_s[(d + 1) * 64 + lane],
            fmaf(q.z, W_s[(d + 2) * 64 + lane],
            fmaf(q.w, W_s[(d + 3) * 64 + lane], acc))));
    }
    ws_base[(size_t)b * 64 + lane] = acc;
    asm volatile("s_waitcnt lgkmcnt(0)" ::: "memory");
  }
}

// ---------------- Kernel B1: ingredient-level attention -> ingre_att [B x 64] ----------------
// lane = w. W column (rows 0..63 of W_att_ingre) lives in 64 registers per lane.
__global__ __launch_bounds__(256, 4)
void ingre_att_kernel(const int* __restrict__ ingre_input,
                      const int* __restrict__ ingre_num,
                      const float* __restrict__ ingre_emb,
                      const float* __restrict__ Wi,    // [192][64], rows 0..63 used
                      const float* __restrict__ v,     // [64]
                      const float* __restrict__ ws_base,
                      float* __restrict__ ws_ia) {
  __shared__ float qe_s[4][NN][64];
  const int t = threadIdx.x;
  const int wave = t >> 6, lane = t & 63;
  float wcol[64];
#pragma unroll
  for (int d = 0; d < 64; ++d) wcol[d] = Wi[d * 64 + lane];
  const float vl = v[lane];
  const int b0 = blockIdx.x * 32 + wave * 8;
#pragma unroll 1
  for (int bi = 0; bi < 8; ++bi) {
    const int b = b0 + bi;
    const int* gp = &ingre_input[b * NN];
#pragma unroll
    for (int n = 0; n < NN; ++n) {
      const int gi = gp[n];
      qe_s[wave][n][lane] = ingre_emb[(size_t)gi * 64 + lane];
    }
    asm volatile("s_waitcnt lgkmcnt(0)" ::: "memory");
    float accn[NN];
#pragma unroll
    for (int n = 0; n < NN; ++n) accn[n] = 0.f;
#pragma unroll
    for (int d0 = 0; d0 < 16; ++d0) {
      const float w0 = wcol[4 * d0 + 0];
      const float w1 = wcol[4 * d0 + 1];
      const float w2 = wcol[4 * d0 + 2];
      const float w3 = wcol[4 * d0 + 3];
#pragma unroll
      for (int n = 0; n < NN; ++n) {
        float4 q = *reinterpret_cast<const float4*>(&qe_s[wave][n][4 * d0]);
        accn[n] = fmaf(q.x, w0, fmaf(q.y, w1, fmaf(q.z, w2, fmaf(q.w, w3, accn[n]))));
      }
    }
    const float base_l = ws_base[(size_t)b * 64 + lane];
#pragma unroll
    for (int n = 0; n < NN; ++n) {
      accn[n] = fast_tanh(accn[n] + base_l) * vl;
    }
    // butterfly reduce all 20 values across the 64 lanes (branch-free, no calls)
#pragma unroll
    for (int off = 1; off < 64; off <<= 1) {
#pragma unroll
      for (int n = 0; n < NN; ++n) accn[n] += __shfl_xor(accn[n], off, 64);
    }
    const int num = ingre_num[b];
    float m = -1e30f;
#pragma unroll
    for (int n = 0; n < NN; ++n) {
      accn[n] = (n < num) ? accn[n] : -1e12f;
      m = fmaxf(m, accn[n]);
    }
    float ssum = 0.f;
#pragma unroll
    for (int n = 0; n < NN; ++n) {
      accn[n] = __expf(accn[n] - m);
      ssum += accn[n];
    }
    const float inv = 1.0f / ssum;
    float ia = 0.f;
#pragma unroll
    for (int n = 0; n < NN; ++n) ia = fmaf(accn[n], qe_s[wave][n][lane], ia);
    ws_ia[(size_t)b * 64 + lane] = ia * inv;
    asm volatile("s_waitcnt lgkmcnt(0)" ::: "memory");
  }
}

// ---------------- Kernel B2: component scores -> flat [3B] (block-concat order) ----------------
__global__ __launch_bounds__(256, 4)
void com_score_kernel(const int* __restrict__ user_input,
                      const int* __restrict__ item_input,
                      const float* __restrict__ user_emb,
                      const float* __restrict__ item_emb,
                      const float* __restrict__ Wc,    // [128][64]
                      const float* __restrict__ Wcb,   // [64]
                      const float* __restrict__ bat,   // [64]
                      const float* __restrict__ vc,    // [64]
                      const float* __restrict__ ws_img,
                      const float* __restrict__ ws_ia,
                      float* __restrict__ ws_flat) {
  __shared__ float Wclds[128 * 64];
  __shared__ float x_s[4][4][64];
  const int t = threadIdx.x;
  for (int i = t; i < 128 * 64 / 4; i += 256)
    reinterpret_cast<float4*>(Wclds)[i] = reinterpret_cast<const float4*>(Wc)[i];
  __syncthreads();
  const int wave = t >> 6, lane = t & 63;
  const float bb = Wcb[lane] + bat[lane];
  const float vcl = vc[lane];
  const int b0 = blockIdx.x * 32 + wave * 8;
#pragma unroll 1
  for (int bi = 0; bi < 8; ++bi) {
    const int b = b0 + bi;
    const int u = user_input[b];
    const int it = item_input[b];
    x_s[wave][0][lane] = user_emb[(size_t)u * 64 + lane];
    x_s[wave][1][lane] = item_emb[(size_t)it * 64 + lane];
    x_s[wave][2][lane] = ws_ia[(size_t)b * 64 + lane];
    x_s[wave][3][lane] = ws_img[(size_t)b * 64 + lane];
    asm volatile("s_waitcnt lgkmcnt(0)" ::: "memory");
    const float4* u4 = reinterpret_cast<const float4*>(&x_s[wave][0][0]);
    float up = 0.f;
#pragma unroll
    for (int d0 = 0; d0 < 16; ++d0) {
      float4 q = u4[d0];
      int d = d0 * 4;
      up = fmaf(q.x, Wclds[(d + 0) * 64 + lane],
           fmaf(q.y, Wclds[(d + 1) * 64 + lane],
           fmaf(q.z, Wclds[(d + 2) * 64 + lane],
           fmaf(q.w, Wclds[(d + 3) * 64 + lane], up))));
    }
    float sc[3];
#pragma unroll
    for (int c = 0; c < 3; ++c) {
      const float4* y4 = reinterpret_cast<const float4*>(&x_s[wave][1 + c][0]);
      float s = bb + up;
#pragma unroll
      for (int d0 = 0; d0 < 16; ++d0) {
        float4 q = y4[d0];
        int d = 64 + d0 * 4;
        s = fmaf(q.x, Wclds[(d + 0) * 64 + lane],
            fmaf(q.y, Wclds[(d + 1) * 64 + lane],
            fmaf(q.z, Wclds[(d + 2) * 64 + lane],
            fmaf(q.w, Wclds[(d + 3) * 64 + lane], s))));
      }
      sc[c] = waveReduceSum(fast_tanh(s) * vcl);
    }
    if (lane == 0) {
      ws_flat[b] = sc[0];
      ws_flat[BB + b] = sc[1];
      ws_flat[2 * BB + b] = sc[2];
    }
    asm volatile("s_waitcnt lgkmcnt(0)" ::: "memory");
  }
}

// ---------------- Kernel C: head. scores[i][j] = flat[3i+j] (faithful reshape quirk) ----------------
__global__ __launch_bounds__(256, 3)
void head_kernel(const int* __restrict__ user_input,
                 const int* __restrict__ item_input,
                 const float* __restrict__ user_emb,
                 const float* __restrict__ item_emb,
                 const float* __restrict__ Wcat,   // [192][64]
                 const float* __restrict__ Wcatb,  // [64]
                 const float* __restrict__ bcat,   // [64]
                 const float* __restrict__ hw,     // [64]
                 const float* __restrict__ hb,     // [1]
                 const float* __restrict__ ws_img,
                 const float* __restrict__ ws_ia,
                 const float* __restrict__ ws_flat,
                 float* __restrict__ out) {
  __shared__ float Wlds[192 * 64];
  __shared__ float ue_s[4][64];
  __shared__ float itt_s[4][64];
  const int t = threadIdx.x;
  for (int i = t; i < 192 * 64 / 4; i += 256)
    reinterpret_cast<float4*>(Wlds)[i] = reinterpret_cast<const float4*>(Wcat)[i];
  __syncthreads();
  const int wave = t >> 6, lane = t & 63;
  const float bb = Wcatb[lane] + bcat[lane];
  const float hwl = hw[lane];
  const float hbv = hb[0];
  const int b0 = blockIdx.x * 32 + wave * 8;
#pragma unroll 1
  for (int bi = 0; bi < 8; ++bi) {
    const int b = b0 + bi;
    const float s0 = ws_flat[3 * b + 0];
    const float s1 = ws_flat[3 * b + 1];
    const float s2 = ws_flat[3 * b + 2];
    const float m = fmaxf(s0, fmaxf(s1, s2));
    const float e0 = __expf(s0 - m), e1 = __expf(s1 - m), e2 = __expf(s2 - m);
    const float inv = 1.0f / (e0 + e1 + e2);
    const int u = user_input[b];
    const int it = item_input[b];
    const float uev = user_emb[(size_t)u * 64 + lane];
    const float itt = (e0 * item_emb[(size_t)it * 64 + lane] +
                       e1 * ws_ia[(size_t)b * 64 + lane] +
                       e2 * ws_img[(size_t)b * 64 + lane]) * inv;
    ue_s[wave][lane] = uev;
    itt_s[wave][lane] = itt;
    asm volatile("s_waitcnt lgkmcnt(0)" ::: "memory");
    const float4* u4 = reinterpret_cast<const float4*>(&ue_s[wave][0]);
    const float4* i4 = reinterpret_cast<const float4*>(&itt_s[wave][0]);
    float h = bb;
#pragma unroll
    for (int d0 = 0; d0 < 16; ++d0) {
      float4 uu = u4[d0];
      float4 ii = i4[d0];
      int d = d0 * 4;
      h = fmaf(uu.x, Wlds[(d + 0) * 64 + lane], h);
      h = fmaf(ii.x, Wlds[(64 + d + 0) * 64 + lane], h);
      h = fmaf(uu.x * ii.x, Wlds[(128 + d + 0) * 64 + lane], h);
      h = fmaf(uu.y, Wlds[(d + 1) * 64 + lane], h);
      h = fmaf(ii.y, Wlds[(64 + d + 1) * 64 + lane], h);
      h = fmaf(uu.y * ii.y, Wlds[(128 + d + 1) * 64 + lane], h);
      h = fmaf(uu.z, Wlds[(d + 2) * 64 + lane], h);
      h = fmaf(ii.z, Wlds[(64 + d + 2) * 64 + lane], h);
      h = fmaf(uu.z * ii.z, Wlds[(128 + d + 2) * 64 + lane], h);
      h = fmaf(uu.w, Wlds[(d + 3) * 64 + lane], h);
      h = fmaf(ii.w, Wlds[(64 + d + 3) * 64 + lane], h);
      h = fmaf(uu.w * ii.w, Wlds[(128 + d + 3) * 64 + lane], h);
    }
    h = fmaxf(h, 0.f) * hwl;
    float o = waveReduceSum(h);
    if (lane == 0) out[b] = o + hbv;
    asm volatile("s_waitcnt lgkmcnt(0)" ::: "memory");
  }
}

extern "C" void kernel_launch(void* const* d_in, const int* in_sizes, int n_in,
                              void* d_out, int out_size, void* d_ws, size_t ws_size,
                              hipStream_t stream) {
  (void)in_sizes; (void)n_in; (void)out_size; (void)ws_size;
  const int* user_input = (const int*)d_in[0];
  const int* item_input = (const int*)d_in[1];
  const int* ingre_input = (const int*)d_in[2];
  const float* image_input = (const float*)d_in[3];
  const int* ingre_num = (const int*)d_in[4];
  const float* user_emb = (const float*)d_in[5];
  const float* item_emb = (const float*)d_in[6];
  const float* ingre_emb = (const float*)d_in[7];
  const float* W_image_w = (const float*)d_in[8];
  const float* W_image_b = (const float*)d_in[9];
  const float* b_image = (const float*)d_in[10];
  const float* W_concat_w = (const float*)d_in[11];
  const float* W_concat_b = (const float*)d_in[12];
  const float* b_concat = (const float*)d_in[13];
  const float* h_w = (const float*)d_in[14];
  const float* h_b = (const float*)d_in[15];
  const float* W_att_ingre_w = (const float*)d_in[16];
  const float* W_att_ingre_b = (const float*)d_in[17];
  const float* b_att_ingre = (const float*)d_in[18];
  const float* v = (const float*)d_in[19];
  const float* W_att_com_w = (const float*)d_in[20];
  const float* W_att_com_b = (const float*)d_in[21];
  const float* b_att_com = (const float*)d_in[22];
  const float* v_c = (const float*)d_in[23];

  float* ws = (float*)d_ws;
  float* ws_img = ws;                              // [B*64]
  float* ws_ia = ws + (size_t)BB * 64;             // [B*64]
  float* ws_base = ws + (size_t)2 * BB * 64;       // [B*64]
  float* ws_flat = ws + (size_t)3 * BB * 64;       // [3B]
  float* out = (float*)d_out;

  img_gemm_kernel<<<BB / 32, 256, 0, stream>>>(image_input, W_image_w, W_image_b,
                                               b_image, ws_img);
  base_kernel<<<BB / 32, 256, 0, stream>>>(user_input, user_emb, ws_img,
                                           W_att_ingre_w, W_att_ingre_b, b_att_ingre,
                                           ws_base);
  ingre_att_kernel<<<BB / 32, 256, 0, stream>>>(ingre_input, ingre_num, ingre_emb,
                                                W_att_ingre_w, v, ws_base, ws_ia);
  com_score_kernel<<<BB / 32, 256, 0, stream>>>(user_input, item_input, user_emb, item_emb,
                                                W_att_com_w, W_att_com_b, b_att_com, v_c,
                                                ws_img, ws_ia, ws_flat);
  head_kernel<<<BB / 32, 256, 0, stream>>>(user_input, item_input, user_emb, item_emb,
                                           W_concat_w, W_concat_b, b_concat, h_w, h_b,
                                           ws_img, ws_ia, ws_flat, out);
}

// Round 3
// 205.329 us; speedup vs baseline: 12.2626x; 1.2816x over previous
//
#include <hip/hip_runtime.h>

#define BB 16384
#define NN 20
#define DD 64
#define IMGK 2048

using bf16x8 = __attribute__((ext_vector_type(8))) short;
using f32x4  = __attribute__((ext_vector_type(4))) float;

__device__ __forceinline__ float waveReduceSum(float x) {
#pragma unroll
  for (int off = 32; off > 0; off >>= 1) x += __shfl_xor(x, off, 64);
  return x;
}

__device__ __forceinline__ float fast_tanh(float x) {
  float e = __expf(2.f * x);
  return 1.f - __fdividef(2.f, e + 1.f);
}

__device__ __forceinline__ short f2bf(float f) {
  union { float f; unsigned u; } c; c.f = f;
  unsigned r = c.u + 0x7fffu + ((c.u >> 16) & 1u);
  return (short)(r >> 16);
}
__device__ __forceinline__ float bf2f(short s) {
  union { unsigned u; float f; } c; c.u = ((unsigned)(unsigned short)s) << 16;
  return c.f;
}

__device__ __forceinline__ unsigned cvt_pk_bf16(float lo, float hi) {
  unsigned r;
  asm("v_cvt_pk_bf16_f32 %0, %1, %2" : "=v"(r) : "v"(lo), "v"(hi));
  return r;
}

__device__ __forceinline__ bf16x8 pack8(float4 a, float4 b) {
  union { unsigned u[4]; bf16x8 v; } r;
  r.u[0] = cvt_pk_bf16(a.x, a.y);
  r.u[1] = cvt_pk_bf16(a.z, a.w);
  r.u[2] = cvt_pk_bf16(b.x, b.y);
  r.u[3] = cvt_pk_bf16(b.z, b.w);
  return r.v;
}

// ---------------- prep: transpose + split weights to bf16 ----------------
// Wt_hi/Wt_lo: [64][2048] from W_image_w [2048][64]; W1t: [64][64] from W_att_ingre rows 0..63
__global__ __launch_bounds__(256)
void prep_kernel(const float* __restrict__ Wimg, const float* __restrict__ W1,
                 short* __restrict__ Wt_hi, short* __restrict__ Wt_lo,
                 short* __restrict__ W1t) {
  int i = blockIdx.x * 256 + threadIdx.x;
  if (i < IMGK * 64) {
    int k = i >> 6, n = i & 63;
    float f = Wimg[i];
    short h = f2bf(f);
    Wt_hi[n * IMGK + k] = h;
    Wt_lo[n * IMGK + k] = f2bf(f - bf2f(h));
  } else if (i < IMGK * 64 + 64 * 64) {
    int j = i - IMGK * 64;
    int k = j >> 6, n = j & 63;
    W1t[n * 64 + k] = f2bf(W1[j]);
  }
}

// ---------------- Kernel A: img GEMM via split-bf16 MFMA ----------------
// [16384 x 2048] @ [2048 x 64]. Block: 32 rows, 4 waves = 2 row-tiles x 2 k-halves.
__global__ __launch_bounds__(256, 2)
void img_gemm_mfma(const float* __restrict__ img_in,
                   const short* __restrict__ Wt_hi,
                   const short* __restrict__ Wt_lo,
                   const float* __restrict__ Wb,
                   const float* __restrict__ bimg,
                   float* __restrict__ img_out) {
  __shared__ float comb[2][16 * 64];
  const int t = threadIdx.x;
  const int wave = t >> 6, lane = t & 63;
  const int rt = wave & 1, kh = wave >> 1;
  const int r0 = blockIdx.x * 32 + rt * 16;
  const int lr = lane & 15, lk = lane >> 4;
  f32x4 aHH[4], aX1[4], aX2[4];
#pragma unroll
  for (int tt = 0; tt < 4; ++tt) {
    aHH[tt] = (f32x4){0.f, 0.f, 0.f, 0.f};
    aX1[tt] = (f32x4){0.f, 0.f, 0.f, 0.f};
    aX2[tt] = (f32x4){0.f, 0.f, 0.f, 0.f};
  }
  const float* arow = img_in + (size_t)(r0 + lr) * IMGK + kh * 1024 + lk * 8;
  const short* wh0 = Wt_hi + (size_t)lr * IMGK + kh * 1024 + lk * 8;
  const short* wl0 = Wt_lo + (size_t)lr * IMGK + kh * 1024 + lk * 8;
#pragma unroll 2
  for (int ks = 0; ks < 32; ++ks) {
    const float4* ap = reinterpret_cast<const float4*>(arow + ks * 32);
    float4 va = ap[0], vb = ap[1];
    union { unsigned u[4]; bf16x8 v; } hi;
    hi.u[0] = cvt_pk_bf16(va.x, va.y);
    hi.u[1] = cvt_pk_bf16(va.z, va.w);
    hi.u[2] = cvt_pk_bf16(vb.x, vb.y);
    hi.u[3] = cvt_pk_bf16(vb.z, vb.w);
    float4 ra, rb;
    ra.x = va.x - __uint_as_float(hi.u[0] << 16);
    ra.y = va.y - __uint_as_float(hi.u[0] & 0xffff0000u);
    ra.z = va.z - __uint_as_float(hi.u[1] << 16);
    ra.w = va.w - __uint_as_float(hi.u[1] & 0xffff0000u);
    rb.x = vb.x - __uint_as_float(hi.u[2] << 16);
    rb.y = vb.y - __uint_as_float(hi.u[2] & 0xffff0000u);
    rb.z = vb.z - __uint_as_float(hi.u[3] << 16);
    rb.w = vb.w - __uint_as_float(hi.u[3] & 0xffff0000u);
    bf16x8 alo = pack8(ra, rb);
#pragma unroll
    for (int tt = 0; tt < 4; ++tt) {
      bf16x8 wh = *reinterpret_cast<const bf16x8*>(wh0 + (size_t)tt * 16 * IMGK + ks * 32);
      bf16x8 wl = *reinterpret_cast<const bf16x8*>(wl0 + (size_t)tt * 16 * IMGK + ks * 32);
      aHH[tt] = __builtin_amdgcn_mfma_f32_16x16x32_bf16(hi.v, wh, aHH[tt], 0, 0, 0);
      aX1[tt] = __builtin_amdgcn_mfma_f32_16x16x32_bf16(hi.v, wl, aX1[tt], 0, 0, 0);
      aX2[tt] = __builtin_amdgcn_mfma_f32_16x16x32_bf16(alo, wh, aX2[tt], 0, 0, 0);
    }
  }
  float val[4][4];
#pragma unroll
  for (int tt = 0; tt < 4; ++tt)
#pragma unroll
    for (int r = 0; r < 4; ++r)
      val[tt][r] = aHH[tt][r] + aX1[tt][r] + aX2[tt][r];
  if (kh == 1) {
#pragma unroll
    for (int tt = 0; tt < 4; ++tt)
#pragma unroll
      for (int r = 0; r < 4; ++r)
        comb[rt][(4 * lk + r) * 64 + 16 * tt + lr] = val[tt][r];
  }
  __syncthreads();
  if (kh == 0) {
#pragma unroll
    for (int tt = 0; tt < 4; ++tt)
#pragma unroll
      for (int r = 0; r < 4; ++r) {
        int n = 16 * tt + lr;
        int row = r0 + 4 * lk + r;
        float o = val[tt][r] + comb[rt][(4 * lk + r) * 64 + n] + Wb[n] + bimg[n];
        img_out[(size_t)row * 64 + n] = o;
      }
  }
}

// ---------------- Kernel A2: base[b][w] = [ue|img] @ Wi[64:192] + Wib + bai ----------------
__global__ __launch_bounds__(256, 4)
void base_kernel(const int* __restrict__ user_input,
                 const float* __restrict__ user_emb,
                 const float* __restrict__ ws_img,
                 const float* __restrict__ Wi,    // [192][64]
                 const float* __restrict__ Wib,   // [64]
                 const float* __restrict__ bai,   // [64]
                 float* __restrict__ ws_base) {
  __shared__ float W_s[128 * 64];
  __shared__ float x_s[4][128];
  const int t = threadIdx.x;
  for (int i = t; i < 128 * 64 / 4; i += 256)
    reinterpret_cast<float4*>(W_s)[i] =
        reinterpret_cast<const float4*>(Wi + 64 * 64)[i];
  __syncthreads();
  const int wave = t >> 6, lane = t & 63;
  const float bb = Wib[lane] + bai[lane];
  const int b0 = blockIdx.x * 32 + wave * 8;
#pragma unroll 1
  for (int bi = 0; bi < 8; ++bi) {
    const int b = b0 + bi;
    const int u = user_input[b];
    x_s[wave][lane] = user_emb[(size_t)u * 64 + lane];
    x_s[wave][64 + lane] = ws_img[(size_t)b * 64 + lane];
    asm volatile("s_waitcnt lgkmcnt(0)" ::: "memory");
    float acc = bb;
    const float4* x4 = reinterpret_cast<const float4*>(&x_s[wave][0]);
#pragma unroll
    for (int d0 = 0; d0 < 32; ++d0) {
      float4 q = x4[d0];
      int d = d0 * 4;
      acc = fmaf(q.x, W_s[(d + 0) * 64 + lane],
            fmaf(q.y, W_s[(d + 1) * 64 + lane],
            fmaf(q.z, W_s[(d + 2) * 64 + lane],
            fmaf(q.w, W_s[(d + 3) * 64 + lane], acc))));
    }
    ws_base[(size_t)b * 64 + lane] = acc;
    asm volatile("s_waitcnt lgkmcnt(0)" ::: "memory");
  }
}

// ---------------- Kernel B1: ingredient attention via MFMA ----------------
// Per b: P[n][w] = qe[20(pad32) x 64] @ W1[64 x 64] via 16 MFMA; tanh; v-sum;
// 16-lane butterfly; LDS score exchange; softmax; ia gather-accumulate.
__global__ __launch_bounds__(256, 2)
void ingre_att_mfma(const int* __restrict__ ingre_input,
                    const int* __restrict__ ingre_num,
                    const float* __restrict__ ingre_emb,
                    const short* __restrict__ W1t,   // [64][64] bf16
                    const float* __restrict__ v,
                    const float* __restrict__ ws_base,
                    float* __restrict__ ws_ia) {
  __shared__ float sc_lds[4][32];
  const int t = threadIdx.x, wave = t >> 6, lane = t & 63;
  const int lr = lane & 15, lk = lane >> 4;
  // preload W1 b-frags [wtile][kstep] and v
  bf16x8 wf[4][2];
#pragma unroll
  for (int wt = 0; wt < 4; ++wt)
#pragma unroll
    for (int ks = 0; ks < 2; ++ks)
      wf[wt][ks] = *reinterpret_cast<const bf16x8*>(
          W1t + (16 * wt + lr) * 64 + ks * 32 + lk * 8);
  float vv[4];
#pragma unroll
  for (int wt = 0; wt < 4; ++wt) vv[wt] = v[16 * wt + lr];
  const int b0 = blockIdx.x * 32 + wave * 8;
#pragma unroll 1
  for (int bi = 0; bi < 8; ++bi) {
    const int b = b0 + bi;
    const int n1 = 16 + lr;
    const int gi0 = ingre_input[b * NN + lr];
    const int gi1 = ingre_input[b * NN + ((n1 < NN) ? n1 : 0)];
    bf16x8 a0[2], a1[2];
#pragma unroll
    for (int ks = 0; ks < 2; ++ks) {
      const float4* p0 = reinterpret_cast<const float4*>(
          ingre_emb + (size_t)gi0 * 64 + ks * 32 + lk * 8);
      a0[ks] = pack8(p0[0], p0[1]);
      const float4* p1 = reinterpret_cast<const float4*>(
          ingre_emb + (size_t)gi1 * 64 + ks * 32 + lk * 8);
      a1[ks] = pack8(p1[0], p1[1]);
    }
    f32x4 acc[2][4];
#pragma unroll
    for (int nt = 0; nt < 2; ++nt)
#pragma unroll
      for (int wt = 0; wt < 4; ++wt) acc[nt][wt] = (f32x4){0.f, 0.f, 0.f, 0.f};
#pragma unroll
    for (int ks = 0; ks < 2; ++ks)
#pragma unroll
      for (int wt = 0; wt < 4; ++wt) {
        acc[0][wt] = __builtin_amdgcn_mfma_f32_16x16x32_bf16(a0[ks], wf[wt][ks], acc[0][wt], 0, 0, 0);
        acc[1][wt] = __builtin_amdgcn_mfma_f32_16x16x32_bf16(a1[ks], wf[wt][ks], acc[1][wt], 0, 0, 0);
      }
    float basew[4];
#pragma unroll
    for (int wt = 0; wt < 4; ++wt) basew[wt] = ws_base[(size_t)b * 64 + 16 * wt + lr];
    float sp[2][4];
#pragma unroll
    for (int nt = 0; nt < 2; ++nt)
#pragma unroll
      for (int r = 0; r < 4; ++r) {
        float s = 0.f;
#pragma unroll
        for (int wt = 0; wt < 4; ++wt) {
          float x = acc[nt][wt][r] + basew[wt];
          s = fmaf(fast_tanh(x), vv[wt], s);
        }
        sp[nt][r] = s;
      }
#pragma unroll
    for (int off = 1; off < 16; off <<= 1)
#pragma unroll
      for (int nt = 0; nt < 2; ++nt)
#pragma unroll
        for (int r = 0; r < 4; ++r) sp[nt][r] += __shfl_xor(sp[nt][r], off, 64);
    if (lr == 0) {
#pragma unroll
      for (int r = 0; r < 4; ++r) {
        sc_lds[wave][4 * lk + r] = sp[0][r];
        sc_lds[wave][16 + 4 * lk + r] = sp[1][r];
      }
    }
    asm volatile("s_waitcnt lgkmcnt(0)" ::: "memory");
    float scn[NN];
#pragma unroll
    for (int q = 0; q < 5; ++q) {
      float4 s4 = *reinterpret_cast<const float4*>(&sc_lds[wave][4 * q]);
      scn[4 * q + 0] = s4.x; scn[4 * q + 1] = s4.y;
      scn[4 * q + 2] = s4.z; scn[4 * q + 3] = s4.w;
    }
    asm volatile("s_waitcnt lgkmcnt(0)" ::: "memory");
    const int num = ingre_num[b];
    float m = -3e38f;
#pragma unroll
    for (int n = 0; n < NN; ++n) {
      scn[n] = (n < num) ? scn[n] : -1e12f;
      m = fmaxf(m, scn[n]);
    }
    float ev[NN], ssum = 0.f;
#pragma unroll
    for (int n = 0; n < NN; ++n) {
      ev[n] = __expf(scn[n] - m);
      ssum += ev[n];
    }
    const float inv = __fdividef(1.f, ssum);
    float qv[NN];
#pragma unroll
    for (int n = 0; n < NN; ++n) {
      const int gi = ingre_input[b * NN + n];
      qv[n] = ingre_emb[(size_t)gi * 64 + lane];
    }
    float ia = 0.f;
#pragma unroll
    for (int n = 0; n < NN; ++n) ia = fmaf(ev[n], qv[n], ia);
    ws_ia[(size_t)b * 64 + lane] = ia * inv;
  }
}

// ---------------- Kernel B2: component scores -> flat [3B] ----------------
__global__ __launch_bounds__(256, 4)
void com_score_kernel(const int* __restrict__ user_input,
                      const int* __restrict__ item_input,
                      const float* __restrict__ user_emb,
                      const float* __restrict__ item_emb,
                      const float* __restrict__ Wc,    // [128][64]
                      const float* __restrict__ Wcb,   // [64]
                      const float* __restrict__ bat,   // [64]
                      const float* __restrict__ vc,    // [64]
                      const float* __restrict__ ws_img,
                      const float* __restrict__ ws_ia,
                      float* __restrict__ ws_flat) {
  __shared__ float Wclds[128 * 64];
  __shared__ float x_s[4][4][64];
  const int t = threadIdx.x;
  for (int i = t; i < 128 * 64 / 4; i += 256)
    reinterpret_cast<float4*>(Wclds)[i] = reinterpret_cast<const float4*>(Wc)[i];
  __syncthreads();
  const int wave = t >> 6, lane = t & 63;
  const float bb = Wcb[lane] + bat[lane];
  const float vcl = vc[lane];
  const int b0 = blockIdx.x * 32 + wave * 8;
#pragma unroll 1
  for (int bi = 0; bi < 8; ++bi) {
    const int b = b0 + bi;
    const int u = user_input[b];
    const int it = item_input[b];
    x_s[wave][0][lane] = user_emb[(size_t)u * 64 + lane];
    x_s[wave][1][lane] = item_emb[(size_t)it * 64 + lane];
    x_s[wave][2][lane] = ws_ia[(size_t)b * 64 + lane];
    x_s[wave][3][lane] = ws_img[(size_t)b * 64 + lane];
    asm volatile("s_waitcnt lgkmcnt(0)" ::: "memory");
    const float4* u4 = reinterpret_cast<const float4*>(&x_s[wave][0][0]);
    float up = 0.f;
#pragma unroll
    for (int d0 = 0; d0 < 16; ++d0) {
      float4 q = u4[d0];
      int d = d0 * 4;
      up = fmaf(q.x, Wclds[(d + 0) * 64 + lane],
           fmaf(q.y, Wclds[(d + 1) * 64 + lane],
           fmaf(q.z, Wclds[(d + 2) * 64 + lane],
           fmaf(q.w, Wclds[(d + 3) * 64 + lane], up))));
    }
    float sc[3];
#pragma unroll
    for (int c = 0; c < 3; ++c) {
      const float4* y4 = reinterpret_cast<const float4*>(&x_s[wave][1 + c][0]);
      float s = bb + up;
#pragma unroll
      for (int d0 = 0; d0 < 16; ++d0) {
        float4 q = y4[d0];
        int d = 64 + d0 * 4;
        s = fmaf(q.x, Wclds[(d + 0) * 64 + lane],
            fmaf(q.y, Wclds[(d + 1) * 64 + lane],
            fmaf(q.z, Wclds[(d + 2) * 64 + lane],
            fmaf(q.w, Wclds[(d + 3) * 64 + lane], s))));
      }
      sc[c] = waveReduceSum(fast_tanh(s) * vcl);
    }
    if (lane == 0) {
      ws_flat[b] = sc[0];
      ws_flat[BB + b] = sc[1];
      ws_flat[2 * BB + b] = sc[2];
    }
    asm volatile("s_waitcnt lgkmcnt(0)" ::: "memory");
  }
}

// ---------------- Kernel C: head. scores[i][j] = flat[3i+j] ----------------
__global__ __launch_bounds__(256, 3)
void head_kernel(const int* __restrict__ user_input,
                 const int* __restrict__ item_input,
                 const float* __restrict__ user_emb,
                 const float* __restrict__ item_emb,
                 const float* __restrict__ Wcat,   // [192][64]
                 const float* __restrict__ Wcatb,  // [64]
                 const float* __restrict__ bcat,   // [64]
                 const float* __restrict__ hw,     // [64]
                 const float* __restrict__ hb,     // [1]
                 const float* __restrict__ ws_img,
                 const float* __restrict__ ws_ia,
                 const float* __restrict__ ws_flat,
                 float* __restrict__ out) {
  __shared__ float Wlds[192 * 64];
  __shared__ float ue_s[4][64];
  __shared__ float itt_s[4][64];
  const int t = threadIdx.x;
  for (int i = t; i < 192 * 64 / 4; i += 256)
    reinterpret_cast<float4*>(Wlds)[i] = reinterpret_cast<const float4*>(Wcat)[i];
  __syncthreads();
  const int wave = t >> 6, lane = t & 63;
  const float bb = Wcatb[lane] + bcat[lane];
  const float hwl = hw[lane];
  const float hbv = hb[0];
  const int b0 = blockIdx.x * 32 + wave * 8;
#pragma unroll 1
  for (int bi = 0; bi < 8; ++bi) {
    const int b = b0 + bi;
    const float s0 = ws_flat[3 * b + 0];
    const float s1 = ws_flat[3 * b + 1];
    const float s2 = ws_flat[3 * b + 2];
    const float m = fmaxf(s0, fmaxf(s1, s2));
    const float e0 = __expf(s0 - m), e1 = __expf(s1 - m), e2 = __expf(s2 - m);
    const float inv = 1.0f / (e0 + e1 + e2);
    const int u = user_input[b];
    const int it = item_input[b];
    const float uev = user_emb[(size_t)u * 64 + lane];
    const float itt = (e0 * item_emb[(size_t)it * 64 + lane] +
                       e1 * ws_ia[(size_t)b * 64 + lane] +
                       e2 * ws_img[(size_t)b * 64 + lane]) * inv;
    ue_s[wave][lane] = uev;
    itt_s[wave][lane] = itt;
    asm volatile("s_waitcnt lgkmcnt(0)" ::: "memory");
    const float4* u4 = reinterpret_cast<const float4*>(&ue_s[wave][0]);
    const float4* i4 = reinterpret_cast<const float4*>(&itt_s[wave][0]);
    float h = bb;
#pragma unroll
    for (int d0 = 0; d0 < 16; ++d0) {
      float4 uu = u4[d0];
      float4 ii = i4[d0];
      int d = d0 * 4;
      h = fmaf(uu.x, Wlds[(d + 0) * 64 + lane], h);
      h = fmaf(ii.x, Wlds[(64 + d + 0) * 64 + lane], h);
      h = fmaf(uu.x * ii.x, Wlds[(128 + d + 0) * 64 + lane], h);
      h = fmaf(uu.y, Wlds[(d + 1) * 64 + lane], h);
      h = fmaf(ii.y, Wlds[(64 + d + 1) * 64 + lane], h);
      h = fmaf(uu.y * ii.y, Wlds[(128 + d + 1) * 64 + lane], h);
      h = fmaf(uu.z, Wlds[(d + 2) * 64 + lane], h);
      h = fmaf(ii.z, Wlds[(64 + d + 2) * 64 + lane], h);
      h = fmaf(uu.z * ii.z, Wlds[(128 + d + 2) * 64 + lane], h);
      h = fmaf(uu.w, Wlds[(d + 3) * 64 + lane], h);
      h = fmaf(ii.w, Wlds[(64 + d + 3) * 64 + lane], h);
      h = fmaf(uu.w * ii.w, Wlds[(128 + d + 3) * 64 + lane], h);
    }
    h = fmaxf(h, 0.f) * hwl;
    float o = waveReduceSum(h);
    if (lane == 0) out[b] = o + hbv;
    asm volatile("s_waitcnt lgkmcnt(0)" ::: "memory");
  }
}

extern "C" void kernel_launch(void* const* d_in, const int* in_sizes, int n_in,
                              void* d_out, int out_size, void* d_ws, size_t ws_size,
                              hipStream_t stream) {
  (void)in_sizes; (void)n_in; (void)out_size; (void)ws_size;
  const int* user_input = (const int*)d_in[0];
  const int* item_input = (const int*)d_in[1];
  const int* ingre_input = (const int*)d_in[2];
  const float* image_input = (const float*)d_in[3];
  const int* ingre_num = (const int*)d_in[4];
  const float* user_emb = (const float*)d_in[5];
  const float* item_emb = (const float*)d_in[6];
  const float* ingre_emb = (const float*)d_in[7];
  const float* W_image_w = (const float*)d_in[8];
  const float* W_image_b = (const float*)d_in[9];
  const float* b_image = (const float*)d_in[10];
  const float* W_concat_w = (const float*)d_in[11];
  const float* W_concat_b = (const float*)d_in[12];
  const float* b_concat = (const float*)d_in[13];
  const float* h_w = (const float*)d_in[14];
  const float* h_b = (const float*)d_in[15];
  const float* W_att_ingre_w = (const float*)d_in[16];
  const float* W_att_ingre_b = (const float*)d_in[17];
  const float* b_att_ingre = (const float*)d_in[18];
  const float* v = (const float*)d_in[19];
  const float* W_att_com_w = (const float*)d_in[20];
  const float* W_att_com_b = (const float*)d_in[21];
  const float* b_att_com = (const float*)d_in[22];
  const float* v_c = (const float*)d_in[23];

  float* ws = (float*)d_ws;
  float* ws_img = ws;                              // [B*64] f32
  float* ws_ia = ws + (size_t)BB * 64;             // [B*64] f32
  float* ws_base = ws + (size_t)2 * BB * 64;       // [B*64] f32
  float* ws_flat = ws + (size_t)3 * BB * 64;       // [3B] f32
  short* Wt_hi = (short*)(ws + (size_t)3 * BB * 64 + 3 * BB);   // [64*2048] bf16
  short* Wt_lo = Wt_hi + (size_t)64 * IMGK;                     // [64*2048] bf16
  short* W1t = Wt_lo + (size_t)64 * IMGK;                       // [64*64] bf16
  float* out = (float*)d_out;

  prep_kernel<<<(IMGK * 64 + 64 * 64 + 255) / 256, 256, 0, stream>>>(
      W_image_w, W_att_ingre_w, Wt_hi, Wt_lo, W1t);
  img_gemm_mfma<<<BB / 32, 256, 0, stream>>>(image_input, Wt_hi, Wt_lo,
                                             W_image_b, b_image, ws_img);
  base_kernel<<<BB / 32, 256, 0, stream>>>(user_input, user_emb, ws_img,
                                           W_att_ingre_w, W_att_ingre_b, b_att_ingre,
                                           ws_base);
  ingre_att_mfma<<<BB / 32, 256, 0, stream>>>(ingre_input, ingre_num, ingre_emb,
                                              W1t, v, ws_base, ws_ia);
  com_score_kernel<<<BB / 32, 256, 0, stream>>>(user_input, item_input, user_emb, item_emb,
                                                W_att_com_w, W_att_com_b, b_att_com, v_c,
                                                ws_img, ws_ia, ws_flat);
  head_kernel<<<BB / 32, 256, 0, stream>>>(user_input, item_input, user_emb, item_emb,
                                           W_concat_w, W_concat_b, b_concat, h_w, h_b,
                                           ws_img, ws_ia, ws_flat, out);
}